// Round 7
// baseline (346.386 us; speedup 1.0000x reference)
//
#include <hip/hip_runtime.h>
#include <hip/hip_bf16.h>
#include <stdint.h>

#define D_MODEL 512
#define N_EXP 8
#define D_FF 2048
#define NTOK 8192
#define TM 256
#define MAX_TILES 72                 /* ceil(16384/256) + 8 */
#define NEPAD (MAX_TILES*TM)         /* 18432 */
#define BK 64

typedef __attribute__((ext_vector_type(8))) short short8;
typedef __attribute__((ext_vector_type(4))) float f32x4;

struct Ctrl {
  int cnt[8];
  int cursor[8];
  int offpad[16];
  int ntiles;
  int pad[3];
  int texp[MAX_TILES];
};

__device__ __forceinline__ unsigned short f2bf(float f){
  unsigned u = __float_as_uint(f);
  u += 0x7FFFu + ((u>>16)&1u);          // RNE
  return (unsigned short)(u>>16);
}
__device__ __forceinline__ float bf2f(unsigned short v){
  return __uint_as_float(((unsigned)v)<<16);
}

__device__ __forceinline__ short8 pack8(float4 a, float4 b){
  short8 o;
  o[0]=(short)f2bf(a.x); o[1]=(short)f2bf(a.y); o[2]=(short)f2bf(a.z); o[3]=(short)f2bf(a.w);
  o[4]=(short)f2bf(b.x); o[5]=(short)f2bf(b.y); o[6]=(short)f2bf(b.z); o[7]=(short)f2bf(b.w);
  return o;
}

__device__ __forceinline__ void gload16(const void* g, void* l){
  __builtin_amdgcn_global_load_lds((const __attribute__((address_space(1))) unsigned int*)g,
                                   (__attribute__((address_space(3))) unsigned int*)l, 16, 0, 0);
}

#define SBAR0 __builtin_amdgcn_sched_barrier(0)
#define BAR   do{ SBAR0; __builtin_amdgcn_s_barrier(); SBAR0; }while(0)
#define LGKM0 do{ asm volatile("s_waitcnt lgkmcnt(0)" ::: "memory"); SBAR0; }while(0)
#define VM0   do{ asm volatile("s_waitcnt vmcnt(0)" ::: "memory"); SBAR0; }while(0)

// ---------------- f32 -> bf16 (up to 3 tensors in one launch) ----------------
__global__ void __launch_bounds__(256)
cvt3_kernel(const float* __restrict__ s0, const float* __restrict__ s1, const float* __restrict__ s2,
            unsigned short* __restrict__ d0, unsigned short* __restrict__ d1, unsigned short* __restrict__ d2){
  const float* src = (blockIdx.y==0) ? s0 : (blockIdx.y==1 ? s1 : s2);
  unsigned short* dst = (blockIdx.y==0) ? d0 : (blockIdx.y==1 ? d1 : d2);
  int i = (blockIdx.x*256 + threadIdx.x)*8;
  float4 a = *(const float4*)(src+i);
  float4 b = *(const float4*)(src+i+4);
  *(short8*)(dst+i) = pack8(a,b);
}

__global__ void __launch_bounds__(256)
cvt_kernel(const float* __restrict__ src, unsigned short* __restrict__ dst, int n){
  int i = (blockIdx.x*256 + threadIdx.x)*8;
  if(i >= n) return;
  float4 a = *(const float4*)(src+i);
  float4 b = *(const float4*)(src+i+4);
  *(short8*)(dst+i) = pack8(a,b);
}

// ---------------- gating: logits->softmax->top2 (+x->bf16) ----------------
__global__ void __launch_bounds__(256)
gate_kernel(const float* __restrict__ x, const float* __restrict__ gw,
            int* __restrict__ tok_e, float* __restrict__ tok_s,
            Ctrl* __restrict__ c, float* __restrict__ Ppart,
            unsigned short* __restrict__ Xb){
  __shared__ float gws[N_EXP*D_MODEL];
  __shared__ float pblk[4][8];
  __shared__ int cblk[8];
  int tid = threadIdx.x;
  for(int i=tid; i<N_EXP*D_MODEL; i+=256) gws[i]=gw[i];
  if(tid<8) cblk[tid]=0;
  __syncthreads();
  int wave = tid>>6, lane = tid&63;
  int t = blockIdx.x*4 + wave;
  const float* xr = x + (size_t)t*D_MODEL + lane*8;
  float4 xa = *(const float4*)xr;
  float4 xb = *(const float4*)(xr+4);
  *(short8*)(Xb + (size_t)t*D_MODEL + lane*8) = pack8(xa,xb);
  float le[8];
  #pragma unroll
  for(int e=0;e<8;e++){
    const float* g = gws + e*D_MODEL + lane*8;
    float4 ga = *(const float4*)g;
    float4 gb = *(const float4*)(g+4);
    le[e] = xa.x*ga.x + xa.y*ga.y + xa.z*ga.z + xa.w*ga.w
          + xb.x*gb.x + xb.y*gb.y + xb.z*gb.z + xb.w*gb.w;
  }
  #pragma unroll
  for(int e=0;e<8;e++){
    float v = le[e];
    #pragma unroll
    for(int off=1; off<64; off<<=1) v += __shfl_xor(v, off);
    le[e]=v;
  }
  float mx = le[0];
  #pragma unroll
  for(int e=1;e<8;e++) mx = fmaxf(mx, le[e]);
  float p[8], s=0.f;
  #pragma unroll
  for(int e=0;e<8;e++){ p[e]=__expf(le[e]-mx); s+=p[e]; }
  float inv = 1.0f/s;
  #pragma unroll
  for(int e=0;e<8;e++) p[e]*=inv;
  int e0=0; float s0=p[0];
  #pragma unroll
  for(int e=1;e<8;e++) if(p[e]>s0){e0=e;s0=p[e];}
  int e1=-1; float s1=-1.f;
  #pragma unroll
  for(int e=0;e<8;e++) if(e!=e0 && p[e]>s1){e1=e;s1=p[e];}
  if(lane==0){
    tok_e[2*t]=e0; tok_e[2*t+1]=e1;
    tok_s[2*t]=s0; tok_s[2*t+1]=s1;
    atomicAdd(&cblk[e0],1); atomicAdd(&cblk[e1],1);
    #pragma unroll
    for(int e=0;e<8;e++) pblk[wave][e]=p[e];
  }
  __syncthreads();
  if(tid<8){
    atomicAdd(&c->cnt[tid], cblk[tid]);
    Ppart[blockIdx.x*8+tid] = pblk[0][tid]+pblk[1][tid]+pblk[2][tid]+pblk[3][tid];
  }
}

// ---------------- scan: offsets, tile map, aux loss ----------------
__global__ void __launch_bounds__(256)
scan_kernel(Ctrl* __restrict__ c, const float* __restrict__ Ppart, float* __restrict__ out){
  __shared__ float red[256];
  __shared__ float tot[8];
  int tid = threadIdx.x;
  for(int e=0;e<8;e++){
    float v=0.f;
    for(int i=tid;i<2048;i+=256) v += Ppart[i*8+e];
    red[tid]=v; __syncthreads();
    for(int s=128;s>0;s>>=1){ if(tid<s) red[tid]+=red[tid+s]; __syncthreads(); }
    if(tid==0) tot[e]=red[0];
    __syncthreads();
  }
  if(tid==0){
    int o=0, tc=0;
    float aux=0.f;
    for(int e=0;e<8;e++){
      c->offpad[e]=o;
      int nt = (c->cnt[e]+TM-1)/TM;
      for(int i=0;i<nt;i++) c->texp[tc++]=e;
      o += nt*TM;
      c->cursor[e]=0;
      aux += ((float)c->cnt[e]/(float)NTOK) * (tot[e]/(float)NTOK);
    }
    c->offpad[8]=o;
    c->ntiles=tc;
    out[(size_t)NTOK*D_MODEL] = 8.0f*0.01f*aux;   // aux_loss slot
  }
}

// ---------------- scatter tokens into per-expert entry lists ----------------
__global__ void __launch_bounds__(256)
scatter_kernel(const int* __restrict__ tok_e, const float* __restrict__ tok_s,
               Ctrl* __restrict__ c, int* __restrict__ etok, float* __restrict__ escl,
               int* __restrict__ pos){
  int t = blockIdx.x*256 + threadIdx.x;
  if(t >= NTOK) return;
  #pragma unroll
  for(int k=0;k<2;k++){
    int e = tok_e[2*t+k];
    int p = atomicAdd(&c->cursor[e],1);
    int i = c->offpad[e]+p;
    etok[i]=t; escl[i]=tok_s[2*t+k];
    pos[2*t+k]=i;
  }
}

// ---------------- phase A: G = silu(X W1^T) * (X V1^T) ----------------
// m97-style: BM=128 entries x BF=64 ff (W & V fused). 256 thr / 4 waves (2M x 2F),
// wave = 64 rows x 32 ff-pair. 64KB LDS -> 2 blocks/CU (cross-block overlap).
// 2-phase loop: STAGE(next); ds_read(cur); lgkm0; 32 MFMA; vmcnt0; barrier.
__global__ void __launch_bounds__(256,2)
expA_kernel(const unsigned short* __restrict__ Xb, const unsigned short* __restrict__ W1b,
            const unsigned short* __restrict__ V1b, const int* __restrict__ etok,
            const Ctrl* __restrict__ c, unsigned short* __restrict__ G){
  __shared__ short8 As[2][1024];   // [buf][row*8 + swz chunk], 128 rows
  __shared__ short8 Bs[2][1024];   // [buf][W rows 0-63 | V rows 0-63]
  int bid = blockIdx.x;            // 4608 = 8 XCD-chunks * (32 fb * 18 mtiles)
  int chunk = bid & 7;
  int w = bid >> 3;                // 0..575 ; fb-outer, mtile-inner (panel L2 reuse)
  int fb = w / 18;
  int mtile = chunk*18 + (w - fb*18);   // 0..143
  if(mtile >= (c->offpad[8] >> 7)) return;
  int e = c->texp[mtile>>1];
  int base = mtile*128;
  int fbase = fb*64;
  int tid = threadIdx.x;

  int r0 = tid>>3, cc = tid&7;
  int cs = cc ^ (r0&7);            // inverse-swizzled source chunk (row&7 == r0&7 for all j)
  const unsigned short* sA0; const unsigned short* sA1;
  const unsigned short* sA2; const unsigned short* sA3;
  { int tok;
    tok = etok[base + r0      ]; sA0 = Xb + (size_t)tok*D_MODEL + cs*8;
    tok = etok[base + r0 + 32 ]; sA1 = Xb + (size_t)tok*D_MODEL + cs*8;
    tok = etok[base + r0 + 64 ]; sA2 = Xb + (size_t)tok*D_MODEL + cs*8;
    tok = etok[base + r0 + 96 ]; sA3 = Xb + (size_t)tok*D_MODEL + cs*8;
  }
  const unsigned short* WE = W1b + (size_t)e*(D_FF*D_MODEL);
  const unsigned short* VE = V1b + (size_t)e*(D_FF*D_MODEL);
  const unsigned short* sW0 = WE + (size_t)(fbase + r0     )*D_MODEL + cs*8;
  const unsigned short* sW1 = WE + (size_t)(fbase + r0 + 32)*D_MODEL + cs*8;
  const unsigned short* sV0 = VE + (size_t)(fbase + r0     )*D_MODEL + cs*8;
  const unsigned short* sV1 = VE + (size_t)(fbase + r0 + 32)*D_MODEL + cs*8;
  int w64 = tid & ~63;

  int lane = tid&63, lrow = lane&15, lk = lane>>4;
  int wv = tid>>6, wm = wv>>1, wf = wv&1;

  f32x4 hacc[4][2], vacc[4][2];
  #pragma unroll
  for(int mi=0;mi<4;mi++)
    #pragma unroll
    for(int fj=0;fj<2;fj++){
      hacc[mi][fj]=(f32x4){0.f,0.f,0.f,0.f};
      vacc[mi][fj]=(f32x4){0.f,0.f,0.f,0.f};
    }

  auto STAGE = [&](int b, int t){
    size_t o = (size_t)t*BK;
    gload16(sA0+o, &As[b][w64      ]);
    gload16(sA1+o, &As[b][w64 + 256]);
    gload16(sA2+o, &As[b][w64 + 512]);
    gload16(sA3+o, &As[b][w64 + 768]);
    gload16(sW0+o, &Bs[b][w64      ]);
    gload16(sW1+o, &Bs[b][w64 + 256]);
    gload16(sV0+o, &Bs[b][w64 + 512]);
    gload16(sV1+o, &Bs[b][w64 + 768]);
  };

  STAGE(0,0);
  VM0; BAR;

  #pragma unroll
  for(int t=0;t<8;t++){
    const int cur = t&1;
    if(t<7) STAGE(cur^1, t+1);
    short8 a[4][2], bw[2][2], bv[2][2];
    #pragma unroll
    for(int ks=0;ks<2;ks++){
      #pragma unroll
      for(int mi=0;mi<4;mi++){
        int arow = wm*64 + mi*16 + lrow;
        a[mi][ks] = As[cur][arow*8 + ((ks*4+lk) ^ (arow&7))];
      }
      #pragma unroll
      for(int fj=0;fj<2;fj++){
        int wrow = wf*32 + fj*16 + lrow;
        int sl = wrow*8 + ((ks*4+lk) ^ (wrow&7));
        bw[fj][ks] = Bs[cur][sl];
        bv[fj][ks] = Bs[cur][512 + sl];
      }
    }
    LGKM0;
    __builtin_amdgcn_s_setprio(1);
    #pragma unroll
    for(int ks=0;ks<2;ks++)
      #pragma unroll
      for(int mi=0;mi<4;mi++)
        #pragma unroll
        for(int fj=0;fj<2;fj++){
          hacc[mi][fj] = __builtin_amdgcn_mfma_f32_16x16x32_bf16(a[mi][ks], bw[fj][ks], hacc[mi][fj],0,0,0);
          vacc[mi][fj] = __builtin_amdgcn_mfma_f32_16x16x32_bf16(a[mi][ks], bv[fj][ks], vacc[mi][fj],0,0,0);
        }
    __builtin_amdgcn_s_setprio(0);
    VM0; BAR;
  }

  #pragma unroll
  for(int mi=0;mi<4;mi++){
    #pragma unroll
    for(int fj=0;fj<2;fj++){
      int f = fbase + wf*32 + fj*16 + lrow;
      #pragma unroll
      for(int r=0;r<4;r++){
        int m = base + wm*64 + mi*16 + lk*4 + r;
        float h = hacc[mi][fj][r], vv = vacc[mi][fj][r];
        float g = (h/(1.0f+__expf(-h)))*vv;
        G[(size_t)m*D_FF + f] = f2bf(g);
      }
    }
  }
}

// ---------------- phase B: Ye = G W2^T (per-entry rows, no atomics) ----------------
// m97-style: BM=128 entries x BN=128 cols, K=2048 (32 K-tiles). 256 thr / 4 waves (2x2),
// wave = 64x64. 64KB LDS -> 2 blocks/CU. Grid 576 -> all CUs busy.
__global__ void __launch_bounds__(256,2)
expB_kernel(const unsigned short* __restrict__ G, const unsigned short* __restrict__ W2b,
            const Ctrl* __restrict__ c, unsigned short* __restrict__ Ye){
  __shared__ short8 As2[2][1024];  // 128 rows x 8 chunks
  __shared__ short8 Bs2[2][1024];  // 128 rows x 8 chunks
  int bid = blockIdx.x;            // 576 = 8 * (4 nb * 18 mtiles)
  int chunk = bid & 7;
  int w = bid >> 3;                // 0..71 ; nb-outer, mtile-inner
  int nb = w / 18;
  int mtile = chunk*18 + (w - nb*18);   // 0..143
  if(mtile >= (c->offpad[8] >> 7)) return;
  int e = c->texp[mtile>>1];
  int base = mtile*128;
  int nbase = nb*128;
  int tid = threadIdx.x;

  int r0 = tid>>3, cc = tid&7;
  int cs = cc ^ (r0&7);
  const unsigned short* sA0 = G + (size_t)(base + r0     )*D_FF + cs*8;
  const unsigned short* sA1 = G + (size_t)(base + r0 + 32)*D_FF + cs*8;
  const unsigned short* sA2 = G + (size_t)(base + r0 + 64)*D_FF + cs*8;
  const unsigned short* sA3 = G + (size_t)(base + r0 + 96)*D_FF + cs*8;
  const unsigned short* W2E = W2b + (size_t)e*(D_MODEL*D_FF);
  const unsigned short* sB0 = W2E + (size_t)(nbase + r0     )*D_FF + cs*8;
  const unsigned short* sB1 = W2E + (size_t)(nbase + r0 + 32)*D_FF + cs*8;
  const unsigned short* sB2 = W2E + (size_t)(nbase + r0 + 64)*D_FF + cs*8;
  const unsigned short* sB3 = W2E + (size_t)(nbase + r0 + 96)*D_FF + cs*8;
  int w64 = tid & ~63;

  int lane = tid&63, lrow = lane&15, lk = lane>>4;
  int wv = tid>>6, wm = wv>>1, wn = wv&1;

  f32x4 acc[4][4];
  #pragma unroll
  for(int mi=0;mi<4;mi++)
    #pragma unroll
    for(int nj=0;nj<4;nj++) acc[mi][nj]=(f32x4){0.f,0.f,0.f,0.f};

  auto STAGE = [&](int b, int t){
    size_t o = (size_t)t*BK;
    gload16(sA0+o, &As2[b][w64      ]);
    gload16(sA1+o, &As2[b][w64 + 256]);
    gload16(sA2+o, &As2[b][w64 + 512]);
    gload16(sA3+o, &As2[b][w64 + 768]);
    gload16(sB0+o, &Bs2[b][w64      ]);
    gload16(sB1+o, &Bs2[b][w64 + 256]);
    gload16(sB2+o, &Bs2[b][w64 + 512]);
    gload16(sB3+o, &Bs2[b][w64 + 768]);
  };

  STAGE(0,0);
  VM0; BAR;

  #pragma unroll 2
  for(int t=0;t<32;t++){
    const int cur = t&1;
    if(t<31) STAGE(cur^1, t+1);
    short8 a[4][2], b[4][2];
    #pragma unroll
    for(int ks=0;ks<2;ks++){
      #pragma unroll
      for(int mi=0;mi<4;mi++){
        int arow = wm*64 + mi*16 + lrow;
        a[mi][ks] = As2[cur][arow*8 + ((ks*4+lk) ^ (arow&7))];
      }
      #pragma unroll
      for(int nj=0;nj<4;nj++){
        int brow = wn*64 + nj*16 + lrow;
        b[nj][ks] = Bs2[cur][brow*8 + ((ks*4+lk) ^ (brow&7))];
      }
    }
    LGKM0;
    __builtin_amdgcn_s_setprio(1);
    #pragma unroll
    for(int ks=0;ks<2;ks++)
      #pragma unroll
      for(int mi=0;mi<4;mi++)
        #pragma unroll
        for(int nj=0;nj<4;nj++)
          acc[mi][nj] = __builtin_amdgcn_mfma_f32_16x16x32_bf16(a[mi][ks], b[nj][ks], acc[mi][nj],0,0,0);
    __builtin_amdgcn_s_setprio(0);
    VM0; BAR;
  }

  #pragma unroll
  for(int mi=0;mi<4;mi++){
    #pragma unroll
    for(int r=0;r<4;r++){
      int m = base + wm*64 + mi*16 + lk*4 + r;
      #pragma unroll
      for(int nj=0;nj<4;nj++){
        int n = nbase + wn*64 + nj*16 + lrow;
        Ye[(size_t)m*D_MODEL + n] = f2bf(acc[mi][nj][r]);
      }
    }
  }
}

// ---------------- combine: out[t] = s0*Ye[p0] + s1*Ye[p1] ----------------
__global__ void __launch_bounds__(256)
combine_kernel(const unsigned short* __restrict__ Ye, const int* __restrict__ pos,
               const float* __restrict__ tok_s, float* __restrict__ out){
  int wave = threadIdx.x>>6, lane = threadIdx.x&63;
  int t = blockIdx.x*4 + wave;
  int p0 = pos[2*t], p1 = pos[2*t+1];
  float s0 = tok_s[2*t], s1 = tok_s[2*t+1];
  short8 y0 = *(const short8*)(Ye + (size_t)p0*D_MODEL + lane*8);
  short8 y1 = *(const short8*)(Ye + (size_t)p1*D_MODEL + lane*8);
  float* o = out + (size_t)t*D_MODEL + lane*8;
  float v[8];
  #pragma unroll
  for(int i=0;i<8;i++)
    v[i] = s0*bf2f((unsigned short)y0[i]) + s1*bf2f((unsigned short)y1[i]);
  float4 lo = {v[0],v[1],v[2],v[3]};
  float4 hi = {v[4],v[5],v[6],v[7]};
  *(float4*)o = lo;
  *(float4*)(o+4) = hi;
}

extern "C" void kernel_launch(void* const* d_in, const int* in_sizes, int n_in,
                              void* d_out, int out_size, void* d_ws, size_t ws_size,
                              hipStream_t stream) {
  (void)in_sizes; (void)n_in; (void)out_size;
  const float* x  = (const float*)d_in[0];
  const float* gw = (const float*)d_in[1];
  const float* W1 = (const float*)d_in[2];
  const float* V1 = (const float*)d_in[3];
  const float* W2 = (const float*)d_in[4];
  float* out = (float*)d_out;

  const size_t WSZ = (size_t)N_EXP*D_FF*D_MODEL;     // 8.39M elems per weight
  const size_t XSZ = (size_t)NTOK*D_MODEL;           // 4.19M
  char* ws = (char*)d_ws;
  size_t off = 0;
  unsigned short* W1b = (unsigned short*)(ws+off); off += WSZ*2;
  unsigned short* V1b = (unsigned short*)(ws+off); size_t v1_off = off; off += WSZ*2;
  unsigned short* Xb  = (unsigned short*)(ws+off); off += XSZ*2;
  unsigned short* G   = (unsigned short*)(ws+off); off += (size_t)NEPAD*D_FF*2;
  int*   etok  = (int*)(ws+off);   size_t entry_off = off; off += (size_t)NEPAD*4;
  float* escl  = (float*)(ws+off); off += (size_t)NEPAD*4;
  size_t entry_bytes = off - entry_off;
  int*   pos   = (int*)(ws+off);   off += (size_t)NTOK*2*4;
  int*   tok_e = (int*)(ws+off);   off += (size_t)NTOK*2*4;
  float* tok_s = (float*)(ws+off); off += (size_t)NTOK*2*4;
  float* Ppart = (float*)(ws+off); off += (size_t)2048*8*4;
  Ctrl*  ctrl  = (Ctrl*)(ws+off);  off += sizeof(Ctrl);
  // Ye (single): 18432*512*2 = 18.87MB, fits V1b(16.78)+Xb(8.39)=25.17MB dead region
  unsigned short* Ye  = (unsigned short*)(ws+v1_off);
  if(ws_size < off) return;

  // optional dedicated W2 buffer (lets W2 cvt run before expA, no serial bubble)
  unsigned short* W2d = (unsigned short*)(ws+off);
  bool hoistW2 = (ws_size >= off + WSZ*2);
  unsigned short* W2b = hoistW2 ? W2d : W1b;

  hipMemsetAsync(ws+entry_off, 0, entry_bytes, stream);
  hipMemsetAsync(ctrl, 0, sizeof(Ctrl), stream);

  cvt3_kernel<<<dim3(4096, hoistW2 ? 3 : 2), 256, 0, stream>>>(W1, V1, W2, W1b, V1b, W2d);

  gate_kernel<<<NTOK/4, 256, 0, stream>>>(x, gw, tok_e, tok_s, ctrl, Ppart, Xb);
  scan_kernel<<<1, 256, 0, stream>>>(ctrl, Ppart, out);
  scatter_kernel<<<NTOK/256, 256, 0, stream>>>(tok_e, tok_s, ctrl, etok, escl, pos);

  expA_kernel<<<4608, 256, 0, stream>>>(Xb, W1b, V1b, etok, ctrl, G);
  if(!hoistW2)
    cvt_kernel<<<(int)WSZ/(256*8), 256, 0, stream>>>(W2, W1b, (int)WSZ);  // into W1b region
  expB_kernel<<<576, 256, 0, stream>>>(G, W2b, ctrl, Ye);
  combine_kernel<<<NTOK/4, 256, 0, stream>>>(Ye, pos, tok_s, out);
}